// Round 4
// baseline (208.496 us; speedup 1.0000x reference)
//
#include <hip/hip_runtime.h>
#include <hip/hip_bf16.h>
#include <math.h>

// Problem constants (B=8, C=256, H=W=64, WS=8, NH=8)
// DTYPES: all inputs fp32, output fp32 (harness compares in bf16 space).
// ws layout (48.02 MiB; AO aliases Q — race-free, see k_attn):
//   Q @ 0, K @ 16 MiB, V @ 32 MiB  [32768][256] bf16 each
//   pooled @ 48 MiB (8 KiB fp32), ca @ +8 KiB (8 KiB fp32)
// d_out (33.55 MiB fp32) doubles as scratch before k_gemm_out2 runs:
//   Ab (gated+permuted bf16 A, 16 MiB) @ 0, Wqb (in_proj W bf16, 384 KiB) @ 16 MiB
// Wob (out_proj W bf16, 128 KiB) reuses the V buffer AFTER k_attn consumed it.
// Softmax scale fold: Q-section of in_proj W and bias pre-multiplied by
// ALPHA = log2(e)/sqrt(32), so attention uses exp2() directly (no per-score mul).
// GEMMs: T3-min 2-phase double-buffered LDS (stage t+1 issued before compute t,
// one vmcnt(0)+barrier per tile) + T1 XCD-contiguous wgid swizzle for A-tile L2 reuse.

typedef unsigned short ushort_t;
typedef unsigned int uint_t;
typedef __attribute__((ext_vector_type(8))) short bf16x8;
typedef __attribute__((ext_vector_type(4))) float f32x4;

#define ALPHA 0.25503486f   // log2(e) / sqrt(32)

__device__ __forceinline__ uint_t pk_rne(float a, float b) {     // bf16 pack, RNE
    __hip_bfloat16 ha = __float2bfloat16(a), hb = __float2bfloat16(b);
    ushort_t ua = *(ushort_t*)&ha, ub = *(ushort_t*)&hb;
    return (uint_t)ua | ((uint_t)ub << 16);
}

// bf16 pack (truncate) via single v_perm_b32: low16 = hi(a), high16 = hi(b)
__device__ __forceinline__ uint_t pk2(float a, float b) {
    union { float f; uint_t u; } ua, ub; ua.f = a; ub.f = b;
    return __builtin_amdgcn_perm(ua.u, ub.u, 0x03020706u);
}

// async global->LDS 16B: LDS dest must be wave-uniform base (+lane*16 implicit)
__device__ __forceinline__ void gl_lds16(const ushort_t* g, ushort_t* l) {
    __builtin_amdgcn_global_load_lds(
        (__attribute__((address_space(1))) unsigned int*)(g),
        (__attribute__((address_space(3))) unsigned int*)(l), 16, 0, 0);
}

// ---------------- Kernel 0: adaptive avg pool -> pooled[b][c] ----------------
__global__ __launch_bounds__(256) void k_pool(const float* __restrict__ x,
                                              float* __restrict__ pooled) {
    int bc = blockIdx.x;
    const float4* row4 = (const float4*)(x + (size_t)bc * 4096);
    float s = 0.f;
    for (int i = threadIdx.x; i < 1024; i += 256) {
        float4 v = row4[i];
        s += v.x + v.y + v.z + v.w;
    }
    __shared__ float red[256];
    red[threadIdx.x] = s;
    __syncthreads();
    for (int o = 128; o > 0; o >>= 1) {
        if (threadIdx.x < o) red[threadIdx.x] += red[threadIdx.x + o];
        __syncthreads();
    }
    if (threadIdx.x == 0) pooled[bc] = red[0] * (1.f / 4096.f);
}

// ---------------- Kernel 1: SE MLP -> ca[b][c] ----------------
__global__ __launch_bounds__(256) void k_se(const float* __restrict__ pooled,
                                            const float* __restrict__ w1,
                                            const float* __restrict__ b1,
                                            const float* __restrict__ w2,
                                            const float* __restrict__ b2,
                                            float* __restrict__ ca) {
    __shared__ float sp[2048];
    __shared__ float sh1[512];
    int t = threadIdx.x;
    for (int i = t; i < 2048; i += 256) sp[i] = pooled[i];
    __syncthreads();
    for (int o = t; o < 512; o += 256) {
        int b = o >> 6, m = o & 63;
        float s = b1[m];
        const float* wr = w1 + (size_t)m * 256;
        const float* pr = sp + b * 256;
        for (int c = 0; c < 256; c++) s += pr[c] * wr[c];
        sh1[o] = s > 0.f ? s : 0.f;
    }
    __syncthreads();
    for (int o = t; o < 2048; o += 256) {
        int b = o >> 8, m = o & 255;
        float s = b2[m];
        const float* wr = w2 + (size_t)m * 64;
        const float* hr = sh1 + b * 64;
        for (int c = 0; c < 64; c++) s += hr[c] * wr[c];
        ca[o] = 1.f / (1.f + __expf(-s));
    }
}

// ------- Kernel 1b: fp32 -> bf16 weight convert, optional head-scale ---------
// elements [0, scale_n8) (in units of 8) are multiplied by `scale` first.
__global__ __launch_bounds__(256) void k_cvt(const float* __restrict__ src,
                                             ushort_t* __restrict__ dst, int n8,
                                             int scale_n8, float scale) {
    int i = blockIdx.x * 256 + threadIdx.x;
    if (i >= n8) return;
    float sc = (i < scale_n8) ? scale : 1.f;
    const float4* s = (const float4*)src + (size_t)i * 2;
    float4 a = s[0], b = s[1];
    uint4 u;
    u.x = pk_rne(a.x * sc, a.y * sc); u.y = pk_rne(a.z * sc, a.w * sc);
    u.z = pk_rne(b.x * sc, b.y * sc); u.w = pk_rne(b.z * sc, b.w * sc);
    *(uint4*)(dst + (size_t)i * 8) = u;
}

// ---------------- Kernel 1c: gate + window-permute + bf16 -> Ab[32768][256] --
#define GPAD 524
__global__ __launch_bounds__(256) void k_gate(const float* __restrict__ x,
                                              const float* __restrict__ ca,
                                              ushort_t* __restrict__ Ab) {
    __shared__ __align__(16) ushort_t Ls[32 * GPAD];
    __shared__ float sca[32];
    int bx = blockIdx.x;
    int b = bx >> 6, hw = (bx >> 3) & 7, c0 = (bx & 7) * 32;
    int t = threadIdx.x;
    if (t < 32) sca[t] = ca[b * 256 + c0 + t];
    __syncthreads();
    const float4* xb = (const float4*)(x + ((size_t)(b * 256 + c0) * 64 + hw * 8) * 64);
#pragma unroll
    for (int i = 0; i < 16; i++) {
        int f = i * 256 + t;
        int ch = f >> 7, rem = f & 127, r = rem >> 4, w4 = rem & 15;
        float4 v = xb[(size_t)ch * 1024 + r * 16 + w4];
        float g = sca[ch];
        uint2 u;
        u.x = pk_rne(v.x * g, v.y * g);
        u.y = pk_rne(v.z * g, v.w * g);
        *(uint2*)&Ls[ch * GPAD + r * 64 + w4 * 4] = u;
    }
    __syncthreads();
#pragma unroll
    for (int i = 0; i < 8; i++) {
        int q = i * 256 + t;
        int rr = q >> 2, part = q & 3;
        int ww = rr >> 6, p = rr & 63;
        int px = (p >> 3) * 64 + ww * 8 + (p & 7);
        const ushort_t* ls = &Ls[part * 8 * GPAD + px];
        uint4 u;
        u.x = (uint_t)ls[0]        | ((uint_t)ls[GPAD] << 16);
        u.y = (uint_t)ls[2 * GPAD] | ((uint_t)ls[3 * GPAD] << 16);
        u.z = (uint_t)ls[4 * GPAD] | ((uint_t)ls[5 * GPAD] << 16);
        u.w = (uint_t)ls[6 * GPAD] | ((uint_t)ls[7 * GPAD] << 16);
        size_t m = (size_t)(((hw * 8 + ww) * 8 + b) * 64 + p);
        *(uint4*)(Ab + m * 256 + c0 + part * 8) = u;
    }
}

// ------- Kernel 2: pure-bf16 MFMA QKV GEMM, 2-phase dbuf + XCD swizzle -------
// C[32768][768] = Ab · Wqb^T. 128x128 tile, BK=64, linear LDS with k-chunk XOR
// swizzle (pre-swizzled global source, same XOR on read). Double-buffered:
// stage(t+1) issued BEFORE compute(t); one vmcnt(0)+barrier per K-step.
// wgid swizzle: XCD k owns y-tiles [k*32,(k+1)*32) -> A-tile (64KB) L2-reused 6x.
__global__ __launch_bounds__(256, 2) void k_gemm_qkv2(const ushort_t* __restrict__ A,
                                                      const ushort_t* __restrict__ Bw,
                                                      const float* __restrict__ bias,
                                                      ushort_t* __restrict__ Qb,
                                                      ushort_t* __restrict__ Kb,
                                                      ushort_t* __restrict__ Vb) {
    __shared__ __align__(16) ushort_t As[2][8192];   // 2 x 16 KiB
    __shared__ __align__(16) ushort_t Bs[2][8192];   // 2 x 16 KiB
    int tid = threadIdx.x;
    int lane = tid & 63, wave = tid >> 6;
    int wm = wave >> 1, wn = wave & 1;
    int col = lane & 15, quad = lane >> 4;
    int orig = blockIdx.x;                    // 0..1535
    int wgid = (orig & 7) * 192 + (orig >> 3);
    int n0 = (wgid % 6) * 128;                // 0..640
    int m0 = (wgid / 6) * 128;
    int cbase = wave * 64 + lane;

    const ushort_t* asrc[4];
    const ushort_t* bsrc[4];
#pragma unroll
    for (int q = 0; q < 4; q++) {
        int c = q * 256 + cbase;             // chunk 0..1023
        int row = c >> 3;
        int kp = (c & 7) ^ (row & 7);        // pre-swizzled source k-part
        asrc[q] = A + (size_t)(m0 + row) * 256 + kp * 8;
        bsrc[q] = Bw + (size_t)(n0 + row) * 256 + kp * 8;
    }

    f32x4 acc[4][4];
#pragma unroll
    for (int i = 0; i < 4; i++)
#pragma unroll
        for (int j = 0; j < 4; j++) acc[i][j] = (f32x4){0.f, 0.f, 0.f, 0.f};

    // prologue: stage K-step 0 into buf 0
#pragma unroll
    for (int q = 0; q < 4; q++) {
        gl_lds16(asrc[q], &As[0][(q * 4 + wave) * 512]);
        gl_lds16(bsrc[q], &Bs[0][(q * 4 + wave) * 512]);
    }
    __syncthreads();

#pragma unroll
    for (int t = 0; t < 4; t++) {
        if (t < 3) {                         // issue next-tile stage early
            int k0 = (t + 1) * 64;
            int nb = (t + 1) & 1;
#pragma unroll
            for (int q = 0; q < 4; q++) {
                gl_lds16(asrc[q] + k0, &As[nb][(q * 4 + wave) * 512]);
                gl_lds16(bsrc[q] + k0, &Bs[nb][(q * 4 + wave) * 512]);
            }
        }
        const ushort_t* Ac = As[t & 1];
        const ushort_t* Bc = Bs[t & 1];
#pragma unroll
        for (int kk = 0; kk < 2; kk++) {
            bf16x8 af[4], bfg[4];
#pragma unroll
            for (int i = 0; i < 4; i++) {
                int row = wm * 64 + i * 16 + col;
                af[i] = *(const bf16x8*)&Ac[row * 64 + ((kk * 4 + quad) ^ (row & 7)) * 8];
            }
#pragma unroll
            for (int j = 0; j < 4; j++) {
                int row = wn * 64 + j * 16 + col;
                bfg[j] = *(const bf16x8*)&Bc[row * 64 + ((kk * 4 + quad) ^ (row & 7)) * 8];
            }
#pragma unroll
            for (int i = 0; i < 4; i++)
#pragma unroll
                for (int j = 0; j < 4; j++)
                    acc[i][j] = __builtin_amdgcn_mfma_f32_16x16x32_bf16(bfg[j], af[i], acc[i][j], 0, 0, 0);
        }
        __syncthreads();                     // drains next stage + lgkm
    }

    // epilogue: n = n0 + wn*64 + j*16 + quad*4 + r ; m = m0 + wm*64 + i*16 + col
    int sec = n0 >> 8;                       // 0=Q,1=K,2=V
    ushort_t* dst = (sec == 0) ? Qb : (sec == 1) ? Kb : Vb;
    float bsc = (sec == 0) ? ALPHA : 1.f;    // Q bias folded with softmax scale
    int nb = (n0 & 255) + wn * 64 + quad * 4;
#pragma unroll
    for (int j = 0; j < 4; j++) {
        float4 bv = *(const float4*)(bias + n0 + wn * 64 + j * 16 + quad * 4);
        bv.x *= bsc; bv.y *= bsc; bv.z *= bsc; bv.w *= bsc;
#pragma unroll
        for (int i = 0; i < 4; i++) {
            int m = m0 + wm * 64 + i * 16 + col;
            uint2 st;
            st.x = pk_rne(acc[i][j][0] + bv.x, acc[i][j][1] + bv.y);
            st.y = pk_rne(acc[i][j][2] + bv.z, acc[i][j][3] + bv.w);
            *(uint2*)(dst + (size_t)m * 256 + nb + j * 16) = st;
        }
    }
}

// ---------------- Kernel 3: MFMA attention per (pixel p, head h) ----------------
// 512 threads (8 waves, 4 q-tiles each), single-shot staging of all 512 keys.
// Ks[key][32] with chunk XOR (quad ^ (key>>3)&3): conflict-free b128 reads.
// Vt[vc][512] transposed; swizzle swz(vc) = (vc&7) ^ ((vc>>3)<<1) on write AND read.
// Q pre-scaled by ALPHA (log2 domain) -> softmax numerator is bare v_exp_f32.
__global__ __launch_bounds__(512, 4) void k_attn(const ushort_t* __restrict__ Qb,
                                                 const ushort_t* __restrict__ Kb,
                                                 const ushort_t* __restrict__ Vb,
                                                 ushort_t* __restrict__ AO) {
    __shared__ __align__(16) ushort_t Ks[512 * 32];   // 32 KiB
    __shared__ __align__(16) ushort_t Vt[32 * 512];   // 32 KiB
    int p = blockIdx.x >> 3, h = blockIdx.x & 7;
    int tid = threadIdx.x;
    int lane = tid & 63, wave = tid >> 6;             // wave 0..7
    int col = lane & 15, quad = lane >> 4;

    // K staging: unit = (key, oct); bf16x8 -> swizzled chunk
#pragma unroll
    for (int it = 0; it < 4; it++) {
        int u = it * 512 + tid;
        int key = u >> 2, oct = u & 3;
        size_t grow = ((size_t)(key * 64 + p)) * 256 + h * 32 + oct * 8;
        int ck = oct ^ ((key >> 3) & 3);
        *(bf16x8*)&Ks[key * 32 + ck * 8] = *(const bf16x8*)(Kb + grow);
    }
    // V staging: unit = (key-pair, oct); pack 2 keys/chan -> ds_write_b32
#pragma unroll
    for (int it = 0; it < 2; it++) {
        int u = it * 512 + tid;
        int kp = u >> 2, oct = u & 3;
        int k0 = kp * 2;
        size_t g0 = ((size_t)(k0 * 64 + p)) * 256 + h * 32 + oct * 8;
        bf16x8 v0 = *(const bf16x8*)(Vb + g0);
        bf16x8 v1 = *(const bf16x8*)(Vb + g0 + 16384);   // key+1 row
        int kc = kp >> 2;                                // key>>3
#pragma unroll
        for (int j = 0; j < 8; j++) {
            int vc = oct * 8 + j;
            int kcs = kc ^ (vc & 7) ^ ((vc >> 3) << 1);
            uint_t pkv = (uint_t)(ushort_t)v0[j] | ((uint_t)(ushort_t)v1[j] << 16);
            *(uint_t*)&Vt[vc * 512 + kcs * 8 + (k0 & 7)] = pkv;
        }
    }

    // Q fragments (independent global loads, overlap with staging)
    bf16x8 qfrag[4];
#pragma unroll
    for (int i = 0; i < 4; i++) {
        int qt = wave * 4 + i;
        qfrag[i] = *(const bf16x8*)(Qb + ((size_t)((qt * 16 + col) * 64 + p)) * 256 + h * 32 + quad * 8);
    }

    f32x4 O0[4], O1[4];
    float qsum[4];
#pragma unroll
    for (int i = 0; i < 4; i++) {
        O0[i] = (f32x4){0.f, 0.f, 0.f, 0.f};
        O1[i] = (f32x4){0.f, 0.f, 0.f, 0.f};
        qsum[i] = 0.f;
    }
    const f32x4 zero = {0.f, 0.f, 0.f, 0.f};
    int R = col >> 2, r4 = lane & 3;
    int krow0 = 8 * R + r4;                  // kf0 row offset; kf1 = +4
    int vc0 = col, vc1 = col + 16;
    int sw0 = (vc0 & 7) ^ ((vc0 >> 3) << 1); // full swizzle, matches write
    int sw1 = (vc1 & 7) ^ ((vc1 >> 3) << 1);

    __syncthreads();

    for (int c = 0; c < 512; c += 32) {
        int row0 = c + krow0;
        int row1 = row0 + 4;
        int ckq = quad ^ ((row0 >> 3) & 3);  // same for row1 (r4<4)
        bf16x8 kf0 = *(const bf16x8*)&Ks[row0 * 32 + ckq * 8];
        bf16x8 kf1 = *(const bf16x8*)&Ks[row1 * 32 + ckq * 8];
        int kc = (c >> 3) + quad;
        bf16x8 vf0 = *(const bf16x8*)&Vt[vc0 * 512 + ((kc ^ sw0) * 8)];
        bf16x8 vf1 = *(const bf16x8*)&Vt[vc1 * 512 + ((kc ^ sw1) * 8)];
#pragma unroll
        for (int i = 0; i < 4; i++) {
            f32x4 s0 = __builtin_amdgcn_mfma_f32_16x16x32_bf16(kf0, qfrag[i], zero, 0, 0, 0);
            f32x4 s1 = __builtin_amdgcn_mfma_f32_16x16x32_bf16(kf1, qfrag[i], zero, 0, 0, 0);
            float p0[4], p1[4];
#pragma unroll
            for (int r = 0; r < 4; r++) {
                p0[r] = __builtin_amdgcn_exp2f(s0[r]);
                p1[r] = __builtin_amdgcn_exp2f(s1[r]);
            }
            qsum[i] += ((p0[0] + p0[1]) + (p0[2] + p0[3])) + ((p1[0] + p1[1]) + (p1[2] + p1[3]));
            union { uint_t u[4]; bf16x8 v; } pb;
            pb.u[0] = pk2(p0[0], p0[1]);
            pb.u[1] = pk2(p0[2], p0[3]);
            pb.u[2] = pk2(p1[0], p1[1]);
            pb.u[3] = pk2(p1[2], p1[3]);
            O0[i] = __builtin_amdgcn_mfma_f32_16x16x32_bf16(vf0, pb.v, O0[i], 0, 0, 0);
            O1[i] = __builtin_amdgcn_mfma_f32_16x16x32_bf16(vf1, pb.v, O1[i], 0, 0, 0);
        }
    }

#pragma unroll
    for (int i = 0; i < 4; i++) {
        float s = qsum[i];
        s += __shfl_xor(s, 16);
        s += __shfl_xor(s, 32);
        float inv = 1.f / s;
        int qt = wave * 4 + i;
        ushort_t* dst = AO + ((size_t)((qt * 16 + col) * 64 + p)) * 256 + h * 32;
        uint2 st0, st1;
        st0.x = pk_rne(O0[i][0] * inv, O0[i][1] * inv);
        st0.y = pk_rne(O0[i][2] * inv, O0[i][3] * inv);
        st1.x = pk_rne(O1[i][0] * inv, O1[i][1] * inv);
        st1.y = pk_rne(O1[i][2] * inv, O1[i][3] * inv);
        *(uint2*)(dst + quad * 4) = st0;
        *(uint2*)(dst + 16 + quad * 4) = st1;
    }
}

// --- Kernel 4: out-proj GEMM + residual + scatter, 2-phase dbuf + XCD swizzle --
__global__ __launch_bounds__(256, 2) void k_gemm_out2(const ushort_t* __restrict__ A,
                                                      const ushort_t* __restrict__ Bw,
                                                      const float* __restrict__ bias,
                                                      const float* __restrict__ x,
                                                      const float* __restrict__ ca,
                                                      float* __restrict__ out) {
    __shared__ __align__(16) ushort_t As[2][8192];
    __shared__ __align__(16) ushort_t Bs[2][8192];
    int tid = threadIdx.x;
    int lane = tid & 63, wave = tid >> 6;
    int wm = wave >> 1, wn = wave & 1;
    int col = lane & 15, quad = lane >> 4;
    int orig = blockIdx.x;                    // 0..511
    int wgid = (orig & 7) * 64 + (orig >> 3);
    int n0 = (wgid & 1) * 128;                // 0 or 128
    int m0 = (wgid >> 1) * 128;
    int cbase = wave * 64 + lane;

    const ushort_t* asrc[4];
    const ushort_t* bsrc[4];
#pragma unroll
    for (int q = 0; q < 4; q++) {
        int c = q * 256 + cbase;
        int row = c >> 3;
        int kp = (c & 7) ^ (row & 7);
        asrc[q] = A + (size_t)(m0 + row) * 256 + kp * 8;
        bsrc[q] = Bw + (size_t)(n0 + row) * 256 + kp * 8;
    }

    f32x4 acc[4][4];
#pragma unroll
    for (int i = 0; i < 4; i++)
#pragma unroll
        for (int j = 0; j < 4; j++) acc[i][j] = (f32x4){0.f, 0.f, 0.f, 0.f};

#pragma unroll
    for (int q = 0; q < 4; q++) {
        gl_lds16(asrc[q], &As[0][(q * 4 + wave) * 512]);
        gl_lds16(bsrc[q], &Bs[0][(q * 4 + wave) * 512]);
    }
    __syncthreads();

#pragma unroll
    for (int t = 0; t < 4; t++) {
        if (t < 3) {
            int k0 = (t + 1) * 64;
            int nb = (t + 1) & 1;
#pragma unroll
            for (int q = 0; q < 4; q++) {
                gl_lds16(asrc[q] + k0, &As[nb][(q * 4 + wave) * 512]);
                gl_lds16(bsrc[q] + k0, &Bs[nb][(q * 4 + wave) * 512]);
            }
        }
        const ushort_t* Ac = As[t & 1];
        const ushort_t* Bc = Bs[t & 1];
#pragma unroll
        for (int kk = 0; kk < 2; kk++) {
            bf16x8 af[4], bfg[4];
#pragma unroll
            for (int i = 0; i < 4; i++) {
                int row = wm * 64 + i * 16 + col;
                af[i] = *(const bf16x8*)&Ac[row * 64 + ((kk * 4 + quad) ^ (row & 7)) * 8];
            }
#pragma unroll
            for (int j = 0; j < 4; j++) {
                int row = wn * 64 + j * 16 + col;
                bfg[j] = *(const bf16x8*)&Bc[row * 64 + ((kk * 4 + quad) ^ (row & 7)) * 8];
            }
#pragma unroll
            for (int i = 0; i < 4; i++)
#pragma unroll
                for (int j = 0; j < 4; j++)
                    acc[i][j] = __builtin_amdgcn_mfma_f32_16x16x32_bf16(bfg[j], af[i], acc[i][j], 0, 0, 0);
        }
        __syncthreads();
    }

    // epilogue: each wave's 64 m-rows = exactly one token lw
    int lw = (m0 + wm * 64) >> 6;
    int b = lw & 7, w_idx = lw >> 3;
#pragma unroll
    for (int j = 0; j < 4; j++) {
        int nbase = n0 + wn * 64 + j * 16 + quad * 4;
        float4 bv = *(const float4*)(bias + nbase);
        float4 cv = *(const float4*)(ca + b * 256 + nbase);
#pragma unroll
        for (int i = 0; i < 4; i++) {
            int p = i * 16 + col;                 // pixel (m_local within token)
#pragma unroll
            for (int r = 0; r < 4; r++) {
                int n = nbase + r;
                float bias_r = (r == 0) ? bv.x : (r == 1) ? bv.y : (r == 2) ? bv.z : bv.w;
                float ca_r = (r == 0) ? cv.x : (r == 1) ? cv.y : (r == 2) ? cv.z : cv.w;
                size_t oi = (((size_t)b * 256 + n) * 64 + w_idx) * 64 + p;
                out[oi] = acc[i][j][r] + bias_r + x[oi] * ca_r;
            }
        }
    }
}

extern "C" void kernel_launch(void* const* d_in, const int* in_sizes, int n_in,
                              void* d_out, int out_size, void* d_ws, size_t ws_size,
                              hipStream_t stream) {
    const float* x     = (const float*)d_in[0];
    const float* ca_w1 = (const float*)d_in[1];
    const float* ca_b1 = (const float*)d_in[2];
    const float* ca_w2 = (const float*)d_in[3];
    const float* ca_b2 = (const float*)d_in[4];
    const float* ipw   = (const float*)d_in[5];
    const float* ipb   = (const float*)d_in[6];
    const float* opw   = (const float*)d_in[7];
    const float* opb   = (const float*)d_in[8];
    float* out = (float*)d_out;

    char* ws = (char*)d_ws;
    const size_t MB16 = 16777216ull;
    ushort_t* Qb = (ushort_t*)(ws + 0);          // 16 MiB; AO aliases this
    ushort_t* Kb = (ushort_t*)(ws + MB16);       // 16 MiB
    ushort_t* Vb = (ushort_t*)(ws + 2 * MB16);   // 16 MiB
    float* pooled = (float*)(ws + 3 * MB16);     // 8 KiB
    float* ca     = (float*)(ws + 3 * MB16 + 8192);

    // d_out as scratch (dead until k_gemm_out2 overwrites all of it):
    ushort_t* Ab  = (ushort_t*)d_out;                       // 16 MiB
    ushort_t* Wqb = (ushort_t*)((char*)d_out + MB16);       // 384 KiB
    // Wob reuses V buffer after k_attn consumed it (stream-ordered):
    ushort_t* Wob = Vb;                                     // 128 KiB

    // Q-section (rows 0..255 = first 8192 groups of 8) scaled by ALPHA
    k_cvt<<<96, 256, 0, stream>>>(ipw, Wqb, 24576, 8192, ALPHA);
    k_pool<<<2048, 256, 0, stream>>>(x, pooled);
    k_se<<<1, 256, 0, stream>>>(pooled, ca_w1, ca_b1, ca_w2, ca_b2, ca);
    k_gate<<<512, 256, 0, stream>>>(x, ca, Ab);
    k_gemm_qkv2<<<1536, 256, 0, stream>>>(Ab, Wqb, ipb, Qb, Kb, Vb);
    k_attn<<<512, 512, 0, stream>>>(Qb, Kb, Vb, Qb /* AO aliases Q */);
    k_cvt<<<32, 256, 0, stream>>>(opw, Wob, 8192, 0, 1.f);
    k_gemm_out2<<<512, 256, 0, stream>>>(Qb, Wob, opb, x, ca, out);
}

// Round 5
// 200.622 us; speedup vs baseline: 1.0392x; 1.0392x over previous
//
#include <hip/hip_runtime.h>
#include <hip/hip_bf16.h>
#include <math.h>

// Problem constants (B=8, C=256, H=W=64, WS=8, NH=8)
// DTYPES: all inputs fp32, output fp32 (harness compares in bf16 space).
// ws layout (48.02 MiB used; AO aliases Q — race-free, see k_attn):
//   Q @ 0, K @ 16 MiB, V @ 32 MiB  [32768][256] bf16 each
//   pooled @ 48 MiB (8 KiB fp32), ca @ +8 KiB (8 KiB fp32)
//   Wob @ +16 KiB (128 KiB bf16) IF ws_size permits, else Wob=Vb post-attn.
// d_out (33.55 MiB fp32) doubles as scratch before k_gemm_out2 runs:
//   Ab (gated+permuted bf16 A, 16 MiB) @ 0, Wqb (in_proj W bf16, 384 KiB) @ 16 MiB
// Softmax scale fold: Q-section of in_proj W pre-scaled by ALPHA = log2(e)/sqrt(32)
// (bias scaled in GEMM epilogue), so attention uses exp2() directly.
// k_gemm_qkv3: m97 structure — single-buffered 2-barrier K-loop, 48 KiB LDS ->
// 3 blocks/CU, grid 768 fully resident; block = (m-tile 128) x (one 256-col
// section); 3 sections of an m-tile sit on the same XCD -> A fetched once.

typedef unsigned short ushort_t;
typedef unsigned int uint_t;
typedef __attribute__((ext_vector_type(8))) short bf16x8;
typedef __attribute__((ext_vector_type(4))) float f32x4;

#define ALPHA 0.25503486f   // log2(e) / sqrt(32)

__device__ __forceinline__ uint_t pk_rne(float a, float b) {     // bf16 pack, RNE
    __hip_bfloat16 ha = __float2bfloat16(a), hb = __float2bfloat16(b);
    ushort_t ua = *(ushort_t*)&ha, ub = *(ushort_t*)&hb;
    return (uint_t)ua | ((uint_t)ub << 16);
}

// bf16 pack (truncate) via single v_perm_b32: low16 = hi(a), high16 = hi(b)
__device__ __forceinline__ uint_t pk2(float a, float b) {
    union { float f; uint_t u; } ua, ub; ua.f = a; ub.f = b;
    return __builtin_amdgcn_perm(ua.u, ub.u, 0x03020706u);
}

// async global->LDS 16B: LDS dest must be wave-uniform base (+lane*16 implicit)
__device__ __forceinline__ void gl_lds16(const ushort_t* g, ushort_t* l) {
    __builtin_amdgcn_global_load_lds(
        (__attribute__((address_space(1))) unsigned int*)(g),
        (__attribute__((address_space(3))) unsigned int*)(l), 16, 0, 0);
}

// ------ Kernel 0: fused pre-pass. blocks 0..2047: avg-pool row bc=bx.
//        blocks 2048..2143: in_proj W fp32->bf16 (Q rows scaled by ALPHA).
//        blocks 2144..2175 (optional): out_proj W fp32->bf16. ------------------
__global__ __launch_bounds__(256) void k_pre(const float* __restrict__ x,
                                             float* __restrict__ pooled,
                                             const float* __restrict__ ipw,
                                             ushort_t* __restrict__ Wqb,
                                             const float* __restrict__ opw,
                                             ushort_t* __restrict__ Wob) {
    int bx = blockIdx.x;
    int t = threadIdx.x;
    if (bx < 2048) {
        const float4* row4 = (const float4*)(x + (size_t)bx * 4096);
        float s = 0.f;
        for (int i = t; i < 1024; i += 256) {
            float4 v = row4[i];
            s += v.x + v.y + v.z + v.w;
        }
        __shared__ float red[256];
        red[t] = s;
        __syncthreads();
        for (int o = 128; o > 0; o >>= 1) {
            if (t < o) red[t] += red[t + o];
            __syncthreads();
        }
        if (t == 0) pooled[bx] = red[0] * (1.f / 4096.f);
    } else if (bx < 2144) {
        int i = (bx - 2048) * 256 + t;            // 0..24575
        float sc = (i < 8192) ? ALPHA : 1.f;      // Q-section rows
        const float4* s4 = (const float4*)ipw + (size_t)i * 2;
        float4 a = s4[0], b = s4[1];
        uint4 u;
        u.x = pk_rne(a.x * sc, a.y * sc); u.y = pk_rne(a.z * sc, a.w * sc);
        u.z = pk_rne(b.x * sc, b.y * sc); u.w = pk_rne(b.z * sc, b.w * sc);
        *(uint4*)(Wqb + (size_t)i * 8) = u;
    } else {
        int i = (bx - 2144) * 256 + t;            // 0..8191
        const float4* s4 = (const float4*)opw + (size_t)i * 2;
        float4 a = s4[0], b = s4[1];
        uint4 u;
        u.x = pk_rne(a.x, a.y); u.y = pk_rne(a.z, a.w);
        u.z = pk_rne(b.x, b.y); u.w = pk_rne(b.z, b.w);
        *(uint4*)(Wob + (size_t)i * 8) = u;
    }
}

// ------- Kernel 1b (fallback when ws too small for early Wob) ----------------
__global__ __launch_bounds__(256) void k_cvt(const float* __restrict__ src,
                                             ushort_t* __restrict__ dst, int n8,
                                             int scale_n8, float scale) {
    int i = blockIdx.x * 256 + threadIdx.x;
    if (i >= n8) return;
    float sc = (i < scale_n8) ? scale : 1.f;
    const float4* s = (const float4*)src + (size_t)i * 2;
    float4 a = s[0], b = s[1];
    uint4 u;
    u.x = pk_rne(a.x * sc, a.y * sc); u.y = pk_rne(a.z * sc, a.w * sc);
    u.z = pk_rne(b.x * sc, b.y * sc); u.w = pk_rne(b.z * sc, b.w * sc);
    *(uint4*)(dst + (size_t)i * 8) = u;
}

// ---------------- Kernel 1: SE MLP -> ca[b][c] ----------------
__global__ __launch_bounds__(256) void k_se(const float* __restrict__ pooled,
                                            const float* __restrict__ w1,
                                            const float* __restrict__ b1,
                                            const float* __restrict__ w2,
                                            const float* __restrict__ b2,
                                            float* __restrict__ ca) {
    __shared__ float sp[2048];
    __shared__ float sh1[512];
    int t = threadIdx.x;
    for (int i = t; i < 2048; i += 256) sp[i] = pooled[i];
    __syncthreads();
    for (int o = t; o < 512; o += 256) {
        int b = o >> 6, m = o & 63;
        float s = b1[m];
        const float* wr = w1 + (size_t)m * 256;
        const float* pr = sp + b * 256;
        for (int c = 0; c < 256; c++) s += pr[c] * wr[c];
        sh1[o] = s > 0.f ? s : 0.f;
    }
    __syncthreads();
    for (int o = t; o < 2048; o += 256) {
        int b = o >> 8, m = o & 255;
        float s = b2[m];
        const float* wr = w2 + (size_t)m * 64;
        const float* hr = sh1 + b * 64;
        for (int c = 0; c < 64; c++) s += hr[c] * wr[c];
        ca[o] = 1.f / (1.f + __expf(-s));
    }
}

// ---------------- Kernel 1c: gate + window-permute + bf16 -> Ab[32768][256] --
#define GPAD 524
__global__ __launch_bounds__(256) void k_gate(const float* __restrict__ x,
                                              const float* __restrict__ ca,
                                              ushort_t* __restrict__ Ab) {
    __shared__ __align__(16) ushort_t Ls[32 * GPAD];
    __shared__ float sca[32];
    int bx = blockIdx.x;
    int b = bx >> 6, hw = (bx >> 3) & 7, c0 = (bx & 7) * 32;
    int t = threadIdx.x;
    if (t < 32) sca[t] = ca[b * 256 + c0 + t];
    __syncthreads();
    const float4* xb = (const float4*)(x + ((size_t)(b * 256 + c0) * 64 + hw * 8) * 64);
#pragma unroll
    for (int i = 0; i < 16; i++) {
        int f = i * 256 + t;
        int ch = f >> 7, rem = f & 127, r = rem >> 4, w4 = rem & 15;
        float4 v = xb[(size_t)ch * 1024 + r * 16 + w4];
        float g = sca[ch];
        uint2 u;
        u.x = pk_rne(v.x * g, v.y * g);
        u.y = pk_rne(v.z * g, v.w * g);
        *(uint2*)&Ls[ch * GPAD + r * 64 + w4 * 4] = u;
    }
    __syncthreads();
#pragma unroll
    for (int i = 0; i < 8; i++) {
        int q = i * 256 + t;
        int rr = q >> 2, part = q & 3;
        int ww = rr >> 6, p = rr & 63;
        int px = (p >> 3) * 64 + ww * 8 + (p & 7);
        const ushort_t* ls = &Ls[part * 8 * GPAD + px];
        uint4 u;
        u.x = (uint_t)ls[0]        | ((uint_t)ls[GPAD] << 16);
        u.y = (uint_t)ls[2 * GPAD] | ((uint_t)ls[3 * GPAD] << 16);
        u.z = (uint_t)ls[4 * GPAD] | ((uint_t)ls[5 * GPAD] << 16);
        u.w = (uint_t)ls[6 * GPAD] | ((uint_t)ls[7 * GPAD] << 16);
        size_t m = (size_t)(((hw * 8 + ww) * 8 + b) * 64 + p);
        *(uint4*)(Ab + m * 256 + c0 + part * 8) = u;
    }
}

// ------- Kernel 2: QKV GEMM, m97-structure (single-buf, 3 blocks/CU) ---------
// Block = 128 m-rows x ONE full 256-col section (sec: 0=Q,1=K,2=V).
// Grid 768 = 3 blocks/CU, all resident; TLP hides the stage drain.
// XCD map: orig&7 = xcd; consecutive blocks on an XCD are the 3 secs of one
// m-tile -> A-tile fetched once from HBM, served from that XCD's L2.
__global__ __launch_bounds__(256, 2) void k_gemm_qkv3(const ushort_t* __restrict__ A,
                                                      const ushort_t* __restrict__ Bw,
                                                      const float* __restrict__ bias,
                                                      ushort_t* __restrict__ Qb,
                                                      ushort_t* __restrict__ Kb,
                                                      ushort_t* __restrict__ Vb) {
    __shared__ __align__(16) ushort_t As[8192];    // 16 KiB: 128 rows x 64 k
    __shared__ __align__(16) ushort_t Bs[16384];   // 32 KiB: 256 rows x 64 k
    int tid = threadIdx.x;
    int lane = tid & 63, wave = tid >> 6;
    int wm = wave >> 1, wn = wave & 1;
    int col = lane & 15, quad = lane >> 4;
    int orig = blockIdx.x;               // 0..767
    int xcd = orig & 7;
    int i96 = orig >> 3;                 // 0..95
    int mi = i96 / 3;                    // 0..31 local m-tile
    int sec = i96 - mi * 3;              // 0..2
    int m0 = (xcd * 32 + mi) * 128;
    const ushort_t* Bsec = Bw + ((size_t)sec << 16);   // sec*256*256

    int cbase = wave * 64 + lane;
    const ushort_t* asrc[4];
    const ushort_t* bsrc[8];
#pragma unroll
    for (int q = 0; q < 4; q++) {
        int c = q * 256 + cbase;         // A chunk 0..1023
        int row = c >> 3;
        int kp = (c & 7) ^ (row & 7);    // pre-swizzled source k-part
        asrc[q] = A + (size_t)(m0 + row) * 256 + kp * 8;
    }
#pragma unroll
    for (int q = 0; q < 8; q++) {
        int c = q * 256 + cbase;         // B chunk 0..2047
        int row = c >> 3;                // 0..255
        int kp = (c & 7) ^ (row & 7);
        bsrc[q] = Bsec + (size_t)row * 256 + kp * 8;
    }

    f32x4 acc[4][8];
#pragma unroll
    for (int i = 0; i < 4; i++)
#pragma unroll
        for (int j = 0; j < 8; j++) acc[i][j] = (f32x4){0.f, 0.f, 0.f, 0.f};

    for (int t = 0; t < 4; t++) {
        int k0 = t * 64;
#pragma unroll
        for (int q = 0; q < 4; q++) gl_lds16(asrc[q] + k0, &As[(q * 4 + wave) * 512]);
#pragma unroll
        for (int q = 0; q < 8; q++) gl_lds16(bsrc[q] + k0, &Bs[(q * 4 + wave) * 512]);
        __syncthreads();
#pragma unroll
        for (int kk = 0; kk < 2; kk++) {
            bf16x8 af[4], bfg[8];
#pragma unroll
            for (int i = 0; i < 4; i++) {
                int row = wm * 64 + i * 16 + col;
                af[i] = *(const bf16x8*)&As[row * 64 + ((kk * 4 + quad) ^ (row & 7)) * 8];
            }
#pragma unroll
            for (int j = 0; j < 8; j++) {
                int row = wn * 128 + j * 16 + col;
                bfg[j] = *(const bf16x8*)&Bs[row * 64 + ((kk * 4 + quad) ^ (row & 7)) * 8];
            }
#pragma unroll
            for (int i = 0; i < 4; i++)
#pragma unroll
                for (int j = 0; j < 8; j++)
                    acc[i][j] = __builtin_amdgcn_mfma_f32_16x16x32_bf16(bfg[j], af[i], acc[i][j], 0, 0, 0);
        }
        __syncthreads();
    }

    // epilogue: n_sec = wn*128 + j*16 + quad*4 + r ; m = m0 + wm*64 + i*16 + col
    ushort_t* dst = (sec == 0) ? Qb : (sec == 1) ? Kb : Vb;
    float bsc = (sec == 0) ? ALPHA : 1.f;    // Q bias folded with softmax scale
    int nb0 = wn * 128 + quad * 4;
#pragma unroll
    for (int j = 0; j < 8; j++) {
        float4 bv = *(const float4*)(bias + sec * 256 + nb0 + j * 16);
        bv.x *= bsc; bv.y *= bsc; bv.z *= bsc; bv.w *= bsc;
#pragma unroll
        for (int i = 0; i < 4; i++) {
            int m = m0 + wm * 64 + i * 16 + col;
            uint2 st;
            st.x = pk_rne(acc[i][j][0] + bv.x, acc[i][j][1] + bv.y);
            st.y = pk_rne(acc[i][j][2] + bv.z, acc[i][j][3] + bv.w);
            *(uint2*)(dst + (size_t)m * 256 + nb0 + j * 16) = st;
        }
    }
}

// ---------------- Kernel 3: MFMA attention per (pixel p, head h) ----------------
// 512 threads (8 waves, 4 q-tiles each), single-shot staging of all 512 keys.
// Ks[key][32] with chunk XOR (quad ^ (key>>3)&3): conflict-free b128 reads.
// Vt[vc][512] transposed; swizzle swz(vc) = (vc&7) ^ ((vc>>3)<<1) on write AND read.
// Q pre-scaled by ALPHA (log2 domain) -> softmax numerator is bare v_exp_f32.
__global__ __launch_bounds__(512, 4) void k_attn(const ushort_t* __restrict__ Qb,
                                                 const ushort_t* __restrict__ Kb,
                                                 const ushort_t* __restrict__ Vb,
                                                 ushort_t* __restrict__ AO) {
    __shared__ __align__(16) ushort_t Ks[512 * 32];   // 32 KiB
    __shared__ __align__(16) ushort_t Vt[32 * 512];   // 32 KiB
    int p = blockIdx.x >> 3, h = blockIdx.x & 7;
    int tid = threadIdx.x;
    int lane = tid & 63, wave = tid >> 6;             // wave 0..7
    int col = lane & 15, quad = lane >> 4;

    // K staging: unit = (key, oct); bf16x8 -> swizzled chunk
#pragma unroll
    for (int it = 0; it < 4; it++) {
        int u = it * 512 + tid;
        int key = u >> 2, oct = u & 3;
        size_t grow = ((size_t)(key * 64 + p)) * 256 + h * 32 + oct * 8;
        int ck = oct ^ ((key >> 3) & 3);
        *(bf16x8*)&Ks[key * 32 + ck * 8] = *(const bf16x8*)(Kb + grow);
    }
    // V staging: unit = (key-pair, oct); pack 2 keys/chan -> ds_write_b32
#pragma unroll
    for (int it = 0; it < 2; it++) {
        int u = it * 512 + tid;
        int kp = u >> 2, oct = u & 3;
        int k0 = kp * 2;
        size_t g0 = ((size_t)(k0 * 64 + p)) * 256 + h * 32 + oct * 8;
        bf16x8 v0 = *(const bf16x8*)(Vb + g0);
        bf16x8 v1 = *(const bf16x8*)(Vb + g0 + 16384);   // key+1 row
        int kc = kp >> 2;                                // key>>3
#pragma unroll
        for (int j = 0; j < 8; j++) {
            int vc = oct * 8 + j;
            int kcs = kc ^ (vc & 7) ^ ((vc >> 3) << 1);
            uint_t pkv = (uint_t)(ushort_t)v0[j] | ((uint_t)(ushort_t)v1[j] << 16);
            *(uint_t*)&Vt[vc * 512 + kcs * 8 + (k0 & 7)] = pkv;
        }
    }

    // Q fragments (independent global loads, overlap with staging)
    bf16x8 qfrag[4];
#pragma unroll
    for (int i = 0; i < 4; i++) {
        int qt = wave * 4 + i;
        qfrag[i] = *(const bf16x8*)(Qb + ((size_t)((qt * 16 + col) * 64 + p)) * 256 + h * 32 + quad * 8);
    }

    f32x4 O0[4], O1[4];
    float qsum[4];
#pragma unroll
    for (int i = 0; i < 4; i++) {
        O0[i] = (f32x4){0.f, 0.f, 0.f, 0.f};
        O1[i] = (f32x4){0.f, 0.f, 0.f, 0.f};
        qsum[i] = 0.f;
    }
    const f32x4 zero = {0.f, 0.f, 0.f, 0.f};
    int R = col >> 2, r4 = lane & 3;
    int krow0 = 8 * R + r4;                  // kf0 row offset; kf1 = +4
    int vc0 = col, vc1 = col + 16;
    int sw0 = (vc0 & 7) ^ ((vc0 >> 3) << 1); // full swizzle, matches write
    int sw1 = (vc1 & 7) ^ ((vc1 >> 3) << 1);

    __syncthreads();

    for (int c = 0; c < 512; c += 32) {
        int row0 = c + krow0;
        int row1 = row0 + 4;
        int ckq = quad ^ ((row0 >> 3) & 3);  // same for row1 (r4<4)
        bf16x8 kf0 = *(const bf16x8*)&Ks[row0 * 32 + ckq * 8];
        bf16x8 kf1 = *(const bf16x8*)&Ks[row1 * 32 + ckq * 8];
        int kc = (c >> 3) + quad;
        bf16x8 vf0 = *(const bf16x8*)&Vt[vc0 * 512 + ((kc ^ sw0) * 8)];
        bf16x8 vf1 = *(const bf16x8*)&Vt[vc1 * 512 + ((kc ^ sw1) * 8)];
#pragma unroll
        for (int i = 0; i < 4; i++) {
            f32x4 s0 = __builtin_amdgcn_mfma_f32_16x16x32_bf16(kf0, qfrag[i], zero, 0, 0, 0);
            f32x4 s1 = __builtin_amdgcn_mfma_f32_16x16x32_bf16(kf1, qfrag[i], zero, 0, 0, 0);
            float p0[4], p1[4];
#pragma unroll
            for (int r = 0; r < 4; r++) {
                p0[r] = __builtin_amdgcn_exp2f(s0[r]);
                p1[r] = __builtin_amdgcn_exp2f(s1[r]);
            }
            qsum[i] += ((p0[0] + p0[1]) + (p0[2] + p0[3])) + ((p1[0] + p1[1]) + (p1[2] + p1[3]));
            union { uint_t u[4]; bf16x8 v; } pb;
            pb.u[0] = pk2(p0[0], p0[1]);
            pb.u[1] = pk2(p0[2], p0[3]);
            pb.u[2] = pk2(p1[0], p1[1]);
            pb.u[3] = pk2(p1[2], p1[3]);
            O0[i] = __builtin_amdgcn_mfma_f32_16x16x32_bf16(vf0, pb.v, O0[i], 0, 0, 0);
            O1[i] = __builtin_amdgcn_mfma_f32_16x16x32_bf16(vf1, pb.v, O1[i], 0, 0, 0);
        }
    }

#pragma unroll
    for (int i = 0; i < 4; i++) {
        float s = qsum[i];
        s += __shfl_xor(s, 16);
        s += __shfl_xor(s, 32);
        float inv = 1.f / s;
        int qt = wave * 4 + i;
        ushort_t* dst = AO + ((size_t)((qt * 16 + col) * 64 + p)) * 256 + h * 32;
        uint2 st0, st1;
        st0.x = pk_rne(O0[i][0] * inv, O0[i][1] * inv);
        st0.y = pk_rne(O0[i][2] * inv, O0[i][3] * inv);
        st1.x = pk_rne(O1[i][0] * inv, O1[i][1] * inv);
        st1.y = pk_rne(O1[i][2] * inv, O1[i][3] * inv);
        *(uint2*)(dst + quad * 4) = st0;
        *(uint2*)(dst + 16 + quad * 4) = st1;
    }
}

// --- Kernel 4: out-proj GEMM + residual + scatter, 2-phase dbuf + XCD swizzle --
__global__ __launch_bounds__(256, 2) void k_gemm_out2(const ushort_t* __restrict__ A,
                                                      const ushort_t* __restrict__ Bw,
                                                      const float* __restrict__ bias,
                                                      const float* __restrict__ x,
                                                      const float* __restrict__ ca,
                                                      float* __restrict__ out) {
    __shared__ __align__(16) ushort_t As[2][8192];
    __shared__ __align__(16) ushort_t Bs[2][8192];
    int tid = threadIdx.x;
    int lane = tid & 63, wave = tid >> 6;
    int wm = wave >> 1, wn = wave & 1;
    int col = lane & 15, quad = lane >> 4;
    int orig = blockIdx.x;                    // 0..511
    int wgid = (orig & 7) * 64 + (orig >> 3);
    int n0 = (wgid & 1) * 128;                // 0 or 128
    int m0 = (wgid >> 1) * 128;
    int cbase = wave * 64 + lane;

    const ushort_t* asrc[4];
    const ushort_t* bsrc[4];
#pragma unroll
    for (int q = 0; q < 4; q++) {
        int c = q * 256 + cbase;
        int row = c >> 3;
        int kp = (c & 7) ^ (row & 7);
        asrc[q] = A + (size_t)(m0 + row) * 256 + kp * 8;
        bsrc[q] = Bw + (size_t)(n0 + row) * 256 + kp * 8;
    }

    f32x4 acc[4][4];
#pragma unroll
    for (int i = 0; i < 4; i++)
#pragma unroll
        for (int j = 0; j < 4; j++) acc[i][j] = (f32x4){0.f, 0.f, 0.f, 0.f};

#pragma unroll
    for (int q = 0; q < 4; q++) {
        gl_lds16(asrc[q], &As[0][(q * 4 + wave) * 512]);
        gl_lds16(bsrc[q], &Bs[0][(q * 4 + wave) * 512]);
    }
    __syncthreads();

#pragma unroll
    for (int t = 0; t < 4; t++) {
        if (t < 3) {
            int k0 = (t + 1) * 64;
            int nb = (t + 1) & 1;
#pragma unroll
            for (int q = 0; q < 4; q++) {
                gl_lds16(asrc[q] + k0, &As[nb][(q * 4 + wave) * 512]);
                gl_lds16(bsrc[q] + k0, &Bs[nb][(q * 4 + wave) * 512]);
            }
        }
        const ushort_t* Ac = As[t & 1];
        const ushort_t* Bc = Bs[t & 1];
#pragma unroll
        for (int kk = 0; kk < 2; kk++) {
            bf16x8 af[4], bfg[4];
#pragma unroll
            for (int i = 0; i < 4; i++) {
                int row = wm * 64 + i * 16 + col;
                af[i] = *(const bf16x8*)&Ac[row * 64 + ((kk * 4 + quad) ^ (row & 7)) * 8];
            }
#pragma unroll
            for (int j = 0; j < 4; j++) {
                int row = wn * 64 + j * 16 + col;
                bfg[j] = *(const bf16x8*)&Bc[row * 64 + ((kk * 4 + quad) ^ (row & 7)) * 8];
            }
#pragma unroll
            for (int i = 0; i < 4; i++)
#pragma unroll
                for (int j = 0; j < 4; j++)
                    acc[i][j] = __builtin_amdgcn_mfma_f32_16x16x32_bf16(bfg[j], af[i], acc[i][j], 0, 0, 0);
        }
        __syncthreads();
    }

    // epilogue: each wave's 64 m-rows = exactly one token lw
    int lw = (m0 + wm * 64) >> 6;
    int b = lw & 7, w_idx = lw >> 3;
#pragma unroll
    for (int j = 0; j < 4; j++) {
        int nbase = n0 + wn * 64 + j * 16 + quad * 4;
        float4 bv = *(const float4*)(bias + nbase);
        float4 cv = *(const float4*)(ca + b * 256 + nbase);
#pragma unroll
        for (int i = 0; i < 4; i++) {
            int p = i * 16 + col;                 // pixel (m_local within token)
#pragma unroll
            for (int r = 0; r < 4; r++) {
                int n = nbase + r;
                float bias_r = (r == 0) ? bv.x : (r == 1) ? bv.y : (r == 2) ? bv.z : bv.w;
                float ca_r = (r == 0) ? cv.x : (r == 1) ? cv.y : (r == 2) ? cv.z : cv.w;
                size_t oi = (((size_t)b * 256 + n) * 64 + w_idx) * 64 + p;
                out[oi] = acc[i][j][r] + bias_r + x[oi] * ca_r;
            }
        }
    }
}

extern "C" void kernel_launch(void* const* d_in, const int* in_sizes, int n_in,
                              void* d_out, int out_size, void* d_ws, size_t ws_size,
                              hipStream_t stream) {
    const float* x     = (const float*)d_in[0];
    const float* ca_w1 = (const float*)d_in[1];
    const float* ca_b1 = (const float*)d_in[2];
    const float* ca_w2 = (const float*)d_in[3];
    const float* ca_b2 = (const float*)d_in[4];
    const float* ipw   = (const float*)d_in[5];
    const float* ipb   = (const float*)d_in[6];
    const float* opw   = (const float*)d_in[7];
    const float* opb   = (const float*)d_in[8];
    float* out = (float*)d_out;

    char* ws = (char*)d_ws;
    const size_t MB16 = 16777216ull;
    ushort_t* Qb = (ushort_t*)(ws + 0);          // 16 MiB; AO aliases this
    ushort_t* Kb = (ushort_t*)(ws + MB16);       // 16 MiB
    ushort_t* Vb = (ushort_t*)(ws + 2 * MB16);   // 16 MiB
    float* pooled = (float*)(ws + 3 * MB16);     // 8 KiB
    float* ca     = (float*)(ws + 3 * MB16 + 8192);

    // d_out as scratch (dead until k_gemm_out2 overwrites all of it):
    ushort_t* Ab  = (ushort_t*)d_out;                       // 16 MiB
    ushort_t* Wqb = (ushort_t*)((char*)d_out + MB16);       // 384 KiB

    // Early Wob (128 KiB) in the ws tail if it fits; else late-cvt into Vb.
    const size_t WOB_OFF = 3 * MB16 + 16384;
    bool wob_early = (ws_size >= WOB_OFF + 131072);
    ushort_t* Wob = wob_early ? (ushort_t*)(ws + WOB_OFF) : Vb;

    k_pre<<<wob_early ? 2176 : 2144, 256, 0, stream>>>(x, pooled, ipw, Wqb, opw, Wob);
    k_se<<<1, 256, 0, stream>>>(pooled, ca_w1, ca_b1, ca_w2, ca_b2, ca);
    k_gate<<<512, 256, 0, stream>>>(x, ca, Ab);
    k_gemm_qkv3<<<768, 256, 0, stream>>>(Ab, Wqb, ipb, Qb, Kb, Vb);
    k_attn<<<512, 512, 0, stream>>>(Qb, Kb, Vb, Qb /* AO aliases Q */);
    if (!wob_early) k_cvt<<<32, 256, 0, stream>>>(opw, Vb, 8192, 0, 1.f);
    k_gemm_out2<<<512, 256, 0, stream>>>(Qb, Wob, opb, x, ca, out);
}